// Round 3
// baseline (900.603 us; speedup 1.0000x reference)
//
#include <hip/hip_runtime.h>
#include <hip/hip_fp16.h>
#include <stdint.h>
#include <stddef.h>

typedef _Float16 f16;
typedef __attribute__((ext_vector_type(4))) _Float16 f16x4;
typedef __attribute__((ext_vector_type(8))) _Float16 f16x8;
typedef __attribute__((ext_vector_type(4))) float f32x4;
typedef __attribute__((ext_vector_type(16))) float f32x16;

// async global->LDS, 16B per lane. LDS dest is wave-uniform base + lane*16.
__device__ __forceinline__ void gld_lds16(const void* g, void* l) {
  __builtin_amdgcn_global_load_lds((const __attribute__((address_space(1))) void*)g,
                                   (__attribute__((address_space(3))) void*)l, 16, 0, 0);
}

// ---------------- fused cast f32 -> f16 for all 5 tensors ----------------
__global__ void cast_all(const float* __restrict__ x, const float* __restrict__ wq,
                         const float* __restrict__ wk, const float* __restrict__ wv,
                         const float* __restrict__ wo, f16* __restrict__ xh,
                         f16* __restrict__ wqh, f16* __restrict__ wkh,
                         f16* __restrict__ wvh, f16* __restrict__ woh) {
  int i = blockIdx.x * blockDim.x + threadIdx.x;
  const float* in;
  f16* out;
  int j = i;
  if (j < 4194304) { in = x; out = xh; }
  else if ((j -= 4194304) < 4194304) { in = wq; out = wqh; }
  else if ((j -= 4194304) < 1048576) { in = wk; out = wkh; }
  else if ((j -= 1048576) < 1048576) { in = wv; out = wvh; }
  else { j -= 1048576; in = wo; out = woh; }
  float4 v = ((const float4*)in)[j];
  f16x4 h;
  h[0] = (f16)v.x; h[1] = (f16)v.y; h[2] = (f16)v.z; h[3] = (f16)v.w;
  *(f16x4*)(out + (size_t)j * 4) = h;
}

// ---------------- GEMM core: C(128x128) = A(128xK) * B(128xK)^T, K=4096 ----------------
// 32x32x16 MFMA (2495 TF ceiling vs 2075 for 16x16), XOR-swizzled LDS, BK=32.
// Wave tile 64x64 = 2x2 of 32x32; 8 MFMA + 8 ds_read_b128 per K-step.
__device__ __forceinline__ void gemm_core_4096(const f16* __restrict__ Ab,
                                               const f16* __restrict__ Bb,
                                               f16* As, f16* Bs, f32x16 acc[2][2]) {
  const int tid = threadIdx.x, ln = tid & 63, wv = tid >> 6;
  const int wr = wv >> 1, wc = wv & 1;
  const int l31 = ln & 31, half = ln >> 5;
#pragma unroll
  for (int a = 0; a < 2; ++a)
#pragma unroll
    for (int b = 0; b < 2; ++b)
#pragma unroll
      for (int r = 0; r < 16; ++r) acc[a][b][r] = 0.f;
  for (int k0 = 0; k0 < 4096; k0 += 32) {
#pragma unroll
    for (int c = 0; c < 2; ++c) {
      int chunk = wv * 2 + c;
      int lrow = chunk * 16 + (ln >> 2);            // tile row this lane stages
      int gcol = ((ln & 3) ^ (lrow & 3)) * 8;       // swizzled source granule
      gld_lds16(Ab + (size_t)lrow * 4096 + k0 + gcol, As + chunk * 512);
      gld_lds16(Bb + (size_t)lrow * 4096 + k0 + gcol, Bs + chunk * 512);
    }
    __syncthreads();
    f16x8 af[2][2], bf[2][2];  // [m-tile][k-step]
#pragma unroll
    for (int tm = 0; tm < 2; ++tm) {
      int row = wr * 64 + tm * 32 + l31;
#pragma unroll
      for (int ks = 0; ks < 2; ++ks) {
        int g = ks * 2 + half;
        af[tm][ks] = *(const f16x8*)&As[row * 32 + ((g ^ (row & 3)) * 8)];
      }
    }
#pragma unroll
    for (int tn = 0; tn < 2; ++tn) {
      int row = wc * 64 + tn * 32 + l31;
#pragma unroll
      for (int ks = 0; ks < 2; ++ks) {
        int g = ks * 2 + half;
        bf[tn][ks] = *(const f16x8*)&Bs[row * 32 + ((g ^ (row & 3)) * 8)];
      }
    }
#pragma unroll
    for (int tm = 0; tm < 2; ++tm)
#pragma unroll
      for (int tn = 0; tn < 2; ++tn) {
        acc[tm][tn] = __builtin_amdgcn_mfma_f32_32x32x16_f16(af[tm][0], bf[tn][0], acc[tm][tn], 0, 0, 0);
        acc[tm][tn] = __builtin_amdgcn_mfma_f32_32x32x16_f16(af[tm][1], bf[tn][1], acc[tm][tn], 0, 0, 0);
      }
    __syncthreads();
  }
}

// ---------------- fused QKV projection ----------------
// grid (48, 32): bx<32 -> Q cols, bx<40 -> K cols, else V cols (written transposed).
__global__ __launch_bounds__(256, 4) void gemm_qkv(
    const f16* __restrict__ xh, const f16* __restrict__ wqh,
    const f16* __restrict__ wkh, const f16* __restrict__ wvh,
    f16* __restrict__ qh, f16* __restrict__ kh, f16* __restrict__ vt) {
  __shared__ __align__(16) f16 As[4096];
  __shared__ __align__(16) f16 Bs[4096];
  const int bx = blockIdx.x, by = blockIdx.y;
  const f16* Bb;
  if (bx < 32)      Bb = wqh + (size_t)bx * 128 * 4096;
  else if (bx < 40) Bb = wkh + (size_t)(bx - 32) * 128 * 4096;
  else              Bb = wvh + (size_t)(bx - 40) * 128 * 4096;
  f32x16 acc[2][2];
  gemm_core_4096(xh + (size_t)by * 128 * 4096, Bb, As, Bs, acc);
  const int tid = threadIdx.x, ln = tid & 63, wv = tid >> 6;
  const int wr = wv >> 1, wc = wv & 1;
  const int l31 = ln & 31, half = ln >> 5;
  // C/D layout (32x32): col = l31, row = (r&3) + 8*(r>>2) + 4*half
#pragma unroll
  for (int tm = 0; tm < 2; ++tm)
#pragma unroll
    for (int tn = 0; tn < 2; ++tn) {
      int colb = wc * 64 + tn * 32 + l31;  // col within the 128-block
#pragma unroll
      for (int g = 0; g < 4; ++g) {
        int mb = by * 128 + wr * 64 + tm * 32 + g * 8 + half * 4;  // token of reg 4g
        if (bx < 32) {
#pragma unroll
          for (int r2 = 0; r2 < 4; ++r2)
            qh[(size_t)(mb + r2) * 4096 + bx * 128 + colb] = (f16)acc[tm][tn][g * 4 + r2];
        } else if (bx < 40) {
#pragma unroll
          for (int r2 = 0; r2 < 4; ++r2)
            kh[(size_t)(mb + r2) * 1024 + (bx - 32) * 128 + colb] = (f16)acc[tm][tn][g * 4 + r2];
        } else {
          f16x4 v4;
#pragma unroll
          for (int r2 = 0; r2 < 4; ++r2) v4[r2] = (f16)acc[tm][tn][g * 4 + r2];
          int n2 = (bx - 40) * 128 + colb;
          int kv = n2 >> 7, d = n2 & 127;
          int bbv = mb >> 11, sl = mb & 2047;  // 4 consecutive tokens, same batch (mb%4==0)
          *(f16x4*)&vt[(((size_t)bbv * 8 + kv) * 128 + d) * 2048 + sl] = v4;
        }
      }
    }
}

// ---------------- RoPE in-place on Q and K (16B per thread) ----------------
__global__ void rope_qk(f16* __restrict__ qh, f16* __restrict__ kh,
                        const float* __restrict__ fc, const float* __restrict__ fs) {
  int i = blockIdx.x * blockDim.x + threadIdx.x;  // granule = 8 f16 = 4 rot pairs
  const int QG = 4096 * 32 * 16;
  f16* ptr;
  int sl, p0;
  if (i < QG) {
    int g = i & 15, head = (i >> 4) & 31, tok = i >> 9;
    sl = tok & 2047; p0 = g * 4;
    ptr = qh + (size_t)tok * 4096 + head * 128 + g * 8;
  } else {
    int j = i - QG;
    int g = j & 15, head = (j >> 4) & 7, tok = j >> 7;
    sl = tok & 2047; p0 = g * 4;
    ptr = kh + (size_t)tok * 1024 + head * 128 + g * 8;
  }
  f16x8 v = *(f16x8*)ptr;
  float4 c = *(const float4*)&fc[sl * 64 + p0];
  float4 s = *(const float4*)&fs[sl * 64 + p0];
  f16x8 o;
  o[0] = (f16)((float)v[0] * c.x - (float)v[1] * s.x);
  o[1] = (f16)((float)v[0] * s.x + (float)v[1] * c.x);
  o[2] = (f16)((float)v[2] * c.y - (float)v[3] * s.y);
  o[3] = (f16)((float)v[2] * s.y + (float)v[3] * c.y);
  o[4] = (f16)((float)v[4] * c.z - (float)v[5] * s.z);
  o[5] = (f16)((float)v[4] * s.z + (float)v[5] * c.z);
  o[6] = (f16)((float)v[6] * c.w - (float)v[7] * s.w);
  o[7] = (f16)((float)v[6] * s.w + (float)v[7] * c.w);
  *(f16x8*)ptr = o;
}

// ---------------- causal GQA flash attention (transposed S/O formulation) ----------------
// grid (32 qtiles, 32 heads, 2 batch), 4 waves, each wave a 16-query strip (q = lane&15).
// S^T = K Q^T  (lane owns query col q=c16 -> in-lane softmax), O^T = V^T P^T.
__global__ __launch_bounds__(256, 4) void attn(
    const f16* __restrict__ qh, const f16* __restrict__ kh,
    const f16* __restrict__ vt, f16* __restrict__ ao) {
  __shared__ __align__(16) f16 Kl[64 * 128];   // [s][d], granule-swizzled g^(s&15)
  __shared__ __align__(16) f16 Vl[128 * 64];   // [d][s], granule-swizzled g^(d&7)
  __shared__ __align__(16) f16 Pl[4][16 * 64]; // per-wave P [q][k], granule-swizzled g^(q&7)
  const int qt = 31 - blockIdx.x;  // longest blocks dispatch first
  const int h = blockIdx.y, bb = blockIdx.z;
  const int kvh = h >> 2;
  const int tid = threadIdx.x, ln = tid & 63, wv = tid >> 6;
  const int quad = ln >> 4, c16 = ln & 15;

  // Q fragment (A/B layout identical): lane holds Q[q=strip row c16][d = ks*32+quad*8+j]
  f16x8 Qf[4];
  {
    size_t qbase = ((size_t)(bb * 2048 + qt * 64 + wv * 16 + c16)) * 4096 + h * 128;
#pragma unroll
    for (int ks = 0; ks < 4; ++ks)
      Qf[ks] = *(const f16x8*)&qh[qbase + ks * 32 + quad * 8];
  }
  float m_run = -INFINITY, l_run = 0.f;
  f32x4 Ot[8];  // O^T tiles over d; lane col = q
#pragma unroll
  for (int n = 0; n < 8; ++n) { f32x4 z = {0.f, 0.f, 0.f, 0.f}; Ot[n] = z; }
  const float scale = 0.08838834764831843f;  // 1/sqrt(128)
  const int qg = qt * 64 + wv * 16 + c16;    // this lane's global query index
  const int swp = ((quad ^ (c16 & 7)) * 8);         // Pl read swizzle, ks=0
  const int swp1 = (((4 + quad) ^ (c16 & 7)) * 8);  // ks=1

  for (int t = 0; t <= qt; ++t) {
    // stage K tile [64][128] and V^T tile [128][64] (swizzled), 4+4 chunks per wave
#pragma unroll
    for (int c = 0; c < 4; ++c) {
      int chunk = wv * 4 + c;
      int krow = chunk * 4 + (ln >> 4);
      int kg = (ln & 15) ^ (krow & 15);
      gld_lds16(&kh[((size_t)(bb * 2048 + t * 64 + krow)) * 1024 + kvh * 128 + kg * 8],
                &Kl[chunk * 512]);
    }
#pragma unroll
    for (int c = 0; c < 4; ++c) {
      int chunk = wv * 4 + c;
      int vrow = chunk * 8 + (ln >> 3);
      int vg = (ln & 7) ^ (vrow & 7);
      gld_lds16(&vt[(((size_t)bb * 8 + kvh) * 128 + vrow) * 2048 + t * 64 + vg * 8],
                &Vl[chunk * 512]);
    }
    __syncthreads();

    // S^T(64x16 per wave): Sa[tn] = K-tile(tn) x Q^T; D[k'=quad*4+r][q=c16]
    f32x4 Sa[4];
#pragma unroll
    for (int tn = 0; tn < 4; ++tn) {
      f32x4 z = {0.f, 0.f, 0.f, 0.f};
      Sa[tn] = z;
#pragma unroll
      for (int ks = 0; ks < 4; ++ks) {
        f16x8 kf = *(const f16x8*)&Kl[(tn * 16 + c16) * 128 + (((ks * 4 + quad) ^ c16) * 8)];
        Sa[tn] = __builtin_amdgcn_mfma_f32_16x16x32_f16(kf, Qf[ks], Sa[tn], 0, 0, 0);
      }
    }

    // scale + causal mask (diagonal tile only)
#pragma unroll
    for (int tn = 0; tn < 4; ++tn)
#pragma unroll
      for (int r = 0; r < 4; ++r) Sa[tn][r] *= scale;
    if (t == qt) {
#pragma unroll
      for (int tn = 0; tn < 4; ++tn) {
        int kbase = t * 64 + tn * 16 + quad * 4;
#pragma unroll
        for (int r = 0; r < 4; ++r)
          if (kbase + r > qg) Sa[tn][r] = -INFINITY;
      }
    }

    // online softmax: per-lane (one q per lane), 2 shuffles per reduction
    float mm = -INFINITY;
#pragma unroll
    for (int tn = 0; tn < 4; ++tn)
#pragma unroll
      for (int r = 0; r < 4; ++r) mm = fmaxf(mm, Sa[tn][r]);
    mm = fmaxf(mm, __shfl_xor(mm, 16, 64));
    mm = fmaxf(mm, __shfl_xor(mm, 32, 64));
    float mn = fmaxf(m_run, mm);
    float alpha = __expf(m_run - mn);
    m_run = mn;
    float rsum = 0.f;
#pragma unroll
    for (int tn = 0; tn < 4; ++tn)
#pragma unroll
      for (int r = 0; r < 4; ++r) {
        float p = __expf(Sa[tn][r] - mn);
        Sa[tn][r] = p;
        rsum += p;
      }
    rsum += __shfl_xor(rsum, 16, 64);
    rsum += __shfl_xor(rsum, 32, 64);
    l_run = l_run * alpha + rsum;

    // P^T (C-layout) -> Pl[q][k] (8B packed, swizzled)
#pragma unroll
    for (int tn = 0; tn < 4; ++tn) {
      f16x4 pk;
#pragma unroll
      for (int r = 0; r < 4; ++r) pk[r] = (f16)Sa[tn][r];
      int g = tn * 2 + (quad >> 1);
      *(f16x4*)&Pl[wv][c16 * 64 + ((g ^ (c16 & 7)) * 8) + (quad & 1) * 4] = pk;
    }

    // rescale O (alpha is a per-lane scalar)
#pragma unroll
    for (int n = 0; n < 8; ++n)
#pragma unroll
      for (int r = 0; r < 4; ++r) Ot[n][r] *= alpha;

    __asm__ volatile("s_waitcnt lgkmcnt(0)" ::: "memory");  // P writes -> P reads (same wave)

    // O^T += V^T P^T : A=V^T[d][k] frags, B=P^T (= rows of Pl[q][k])
    {
      f16x8 pf0 = *(const f16x8*)&Pl[wv][c16 * 64 + swp];
      f16x8 pf1 = *(const f16x8*)&Pl[wv][c16 * 64 + swp1];
#pragma unroll
      for (int n = 0; n < 8; ++n) {
        int rowv = (n * 16 + c16) * 64;
        f16x8 vf0 = *(const f16x8*)&Vl[rowv + swp];
        Ot[n] = __builtin_amdgcn_mfma_f32_16x16x32_f16(vf0, pf0, Ot[n], 0, 0, 0);
        f16x8 vf1 = *(const f16x8*)&Vl[rowv + swp1];
        Ot[n] = __builtin_amdgcn_mfma_f32_16x16x32_f16(vf1, pf1, Ot[n], 0, 0, 0);
      }
    }
    __syncthreads();
  }

  // epilogue: O = O^T normalized; lane writes 4 contiguous d per tile (8B stores)
  float inv = 1.0f / l_run;
  size_t token = (size_t)(bb * 2048 + qt * 64 + wv * 16 + c16);
#pragma unroll
  for (int n = 0; n < 8; ++n) {
    f16x4 o;
#pragma unroll
    for (int r = 0; r < 4; ++r) o[r] = (f16)(Ot[n][r] * inv);
    *(f16x4*)&ao[token * 4096 + h * 128 + n * 16 + quad * 4] = o;
  }
}

// ---------------- output projection: out = ao @ wo^T (fp32 out) ----------------
__global__ __launch_bounds__(256, 4) void gemm_out(
    const f16* __restrict__ ao, const f16* __restrict__ woh, float* __restrict__ out) {
  __shared__ __align__(16) f16 As[4096];
  __shared__ __align__(16) f16 Bs[4096];
  f32x16 acc[2][2];
  gemm_core_4096(ao + (size_t)blockIdx.y * 128 * 4096,
                 woh + (size_t)blockIdx.x * 128 * 4096, As, Bs, acc);
  const int tid = threadIdx.x, ln = tid & 63, wv = tid >> 6;
  const int wr = wv >> 1, wc = wv & 1;
  const int l31 = ln & 31, half = ln >> 5;
#pragma unroll
  for (int tm = 0; tm < 2; ++tm)
#pragma unroll
    for (int tn = 0; tn < 2; ++tn) {
      int n = blockIdx.x * 128 + wc * 64 + tn * 32 + l31;
#pragma unroll
      for (int g = 0; g < 4; ++g) {
        int mb = blockIdx.y * 128 + wr * 64 + tm * 32 + g * 8 + half * 4;
#pragma unroll
        for (int r2 = 0; r2 < 4; ++r2)
          out[(size_t)(mb + r2) * 4096 + n] = acc[tm][tn][g * 4 + r2];
      }
    }
}

// ---------------- launch ----------------
extern "C" void kernel_launch(void* const* d_in, const int* in_sizes, int n_in,
                              void* d_out, int out_size, void* d_ws, size_t ws_size,
                              hipStream_t stream) {
  const float* x  = (const float*)d_in[0];
  const float* wq = (const float*)d_in[1];
  const float* wk = (const float*)d_in[2];
  const float* wv = (const float*)d_in[3];
  const float* wo = (const float*)d_in[4];
  const float* fc = (const float*)d_in[5];
  const float* fs = (const float*)d_in[6];
  float* out = (float*)d_out;

  char* ws = (char*)d_ws;
  f16* xh  = (f16*)(ws + 0);          // 32 MiB  x fp16 [4096][4096]
  f16* wqh = (f16*)(ws + 33554432);   // 32 MiB
  f16* wkh = (f16*)(ws + 67108864);   // 8 MiB
  f16* wvh = (f16*)(ws + 75497472);   // 8 MiB
  f16* woh = (f16*)(ws + 83886080);   // 32 MiB
  f16* qh  = (f16*)(ws + 117440512);  // 32 MiB  Q [4096][4096]
  f16* kh  = (f16*)(ws + 150994944);  // 8 MiB   K [4096][1024]
  f16* vt  = (f16*)(ws + 159383552);  // 8 MiB   V^T [2][8][128][2048]
  f16* ao  = (f16*)(ws + 167772160);  // 32 MiB  attn out [4096][4096]

  cast_all<<<57344, 256, 0, stream>>>(x, wq, wk, wv, wo, xh, wqh, wkh, wvh, woh);
  gemm_qkv<<<dim3(48, 32), 256, 0, stream>>>(xh, wqh, wkh, wvh, qh, kh, vt);
  rope_qk<<<10240, 256, 0, stream>>>(qh, kh, fc, fs);
  attn<<<dim3(32, 32, 2), 256, 0, stream>>>(qh, kh, vt, ao);
  gemm_out<<<dim3(32, 32), 256, 0, stream>>>(ao, woh, out);
}

// Round 4
// 870.707 us; speedup vs baseline: 1.0343x; 1.0343x over previous
//
#include <hip/hip_runtime.h>
#include <hip/hip_fp16.h>
#include <stdint.h>
#include <stddef.h>

typedef _Float16 f16;
typedef __attribute__((ext_vector_type(4))) _Float16 f16x4;
typedef __attribute__((ext_vector_type(8))) _Float16 f16x8;
typedef __attribute__((ext_vector_type(4))) float f32x4;
typedef __attribute__((ext_vector_type(16))) float f32x16;

// async global->LDS, 16B per lane. LDS dest is wave-uniform base + lane*16.
__device__ __forceinline__ void gld_lds16(const void* g, void* l) {
  __builtin_amdgcn_global_load_lds((const __attribute__((address_space(1))) void*)g,
                                   (__attribute__((address_space(3))) void*)l, 16, 0, 0);
}

// ---------------- fused cast f32 -> f16 for all 5 tensors ----------------
__global__ void cast_all(const float* __restrict__ x, const float* __restrict__ wq,
                         const float* __restrict__ wk, const float* __restrict__ wv,
                         const float* __restrict__ wo, f16* __restrict__ xh,
                         f16* __restrict__ wqh, f16* __restrict__ wkh,
                         f16* __restrict__ wvh, f16* __restrict__ woh) {
  int i = blockIdx.x * blockDim.x + threadIdx.x;
  const float* in;
  f16* out;
  int j = i;
  if (j < 4194304) { in = x; out = xh; }
  else if ((j -= 4194304) < 4194304) { in = wq; out = wqh; }
  else if ((j -= 4194304) < 1048576) { in = wk; out = wkh; }
  else if ((j -= 1048576) < 1048576) { in = wv; out = wvh; }
  else { j -= 1048576; in = wo; out = woh; }
  float4 v = ((const float4*)in)[j];
  f16x4 h;
  h[0] = (f16)v.x; h[1] = (f16)v.y; h[2] = (f16)v.z; h[3] = (f16)v.w;
  *(f16x4*)(out + (size_t)j * 4) = h;
}

// ---------------- GEMM core: C(128x128) = A(128xK) * B(128xK)^T, K=4096 ----------------
// 32x32x16 MFMA + conflict-free 3-bit XOR LDS swizzle:
//   tile = 64 lines of 128B (2 rows each); logical slot s=(r&1)*4+c stored at s^(line&7).
//   Every 8 consecutive lanes of a fragment ds_read_b128 hit all 8 bank groups.
__device__ __forceinline__ void gemm_core_4096(const f16* __restrict__ Ab,
                                               const f16* __restrict__ Bb,
                                               f16* As, f16* Bs, f32x16 acc[2][2]) {
  const int tid = threadIdx.x, ln = tid & 63, wv = tid >> 6;
  const int wr = wv >> 1, wc = wv & 1;
  const int l31 = ln & 31, half = ln >> 5;
#pragma unroll
  for (int a = 0; a < 2; ++a)
#pragma unroll
    for (int b = 0; b < 2; ++b)
#pragma unroll
      for (int r = 0; r < 16; ++r) acc[a][b][r] = 0.f;

  // staging map: chunk ch stages physical granules P=ch*64+ln; invert swizzle for global src
  int srow[2], scol[2];
#pragma unroll
  for (int c = 0; c < 2; ++c) {
    int chunk = wv * 2 + c;
    int lineL = chunk * 8 + (ln >> 3);
    int s = (ln & 7) ^ (lineL & 7);
    srow[c] = lineL * 2 + (s >> 2);
    scol[c] = (s & 3) * 8;
  }
  // fragment-read swizzle constant: s' = (ks*2+half) ^ bxor, line = base/2 + (l31>>1)
  const int rb = l31 >> 1;
  const int bxor = ((l31 & 1) * 4) ^ (rb & 7);

  for (int k0 = 0; k0 < 4096; k0 += 32) {
#pragma unroll
    for (int c = 0; c < 2; ++c) {
      int chunk = wv * 2 + c;
      gld_lds16(Ab + (size_t)srow[c] * 4096 + k0 + scol[c], As + chunk * 512);
      gld_lds16(Bb + (size_t)srow[c] * 4096 + k0 + scol[c], Bs + chunk * 512);
    }
    __syncthreads();
    f16x8 af[2][2], bf[2][2];  // [m-tile][k-step]
#pragma unroll
    for (int tm = 0; tm < 2; ++tm) {
      int lbase = (wr * 32 + tm * 16 + rb) * 64;
#pragma unroll
      for (int ks = 0; ks < 2; ++ks)
        af[tm][ks] = *(const f16x8*)&As[lbase + (((ks * 2 + half) ^ bxor) * 8)];
    }
#pragma unroll
    for (int tn = 0; tn < 2; ++tn) {
      int lbase = (wc * 32 + tn * 16 + rb) * 64;
#pragma unroll
      for (int ks = 0; ks < 2; ++ks)
        bf[tn][ks] = *(const f16x8*)&Bs[lbase + (((ks * 2 + half) ^ bxor) * 8)];
    }
#pragma unroll
    for (int tm = 0; tm < 2; ++tm)
#pragma unroll
      for (int tn = 0; tn < 2; ++tn) {
        acc[tm][tn] = __builtin_amdgcn_mfma_f32_32x32x16_f16(af[tm][0], bf[tn][0], acc[tm][tn], 0, 0, 0);
        acc[tm][tn] = __builtin_amdgcn_mfma_f32_32x32x16_f16(af[tm][1], bf[tn][1], acc[tm][tn], 0, 0, 0);
      }
    __syncthreads();
  }
}

// ---------------- fused QKV projection ----------------
// grid (48, 32): bx<32 -> Q cols, bx<40 -> K cols, else V cols (written transposed).
__global__ __launch_bounds__(256, 4) void gemm_qkv(
    const f16* __restrict__ xh, const f16* __restrict__ wqh,
    const f16* __restrict__ wkh, const f16* __restrict__ wvh,
    f16* __restrict__ qh, f16* __restrict__ kh, f16* __restrict__ vt) {
  __shared__ __align__(16) f16 As[4096];
  __shared__ __align__(16) f16 Bs[4096];
  const int bx = blockIdx.x, by = blockIdx.y;
  const f16* Bb;
  if (bx < 32)      Bb = wqh + (size_t)bx * 128 * 4096;
  else if (bx < 40) Bb = wkh + (size_t)(bx - 32) * 128 * 4096;
  else              Bb = wvh + (size_t)(bx - 40) * 128 * 4096;
  f32x16 acc[2][2];
  gemm_core_4096(xh + (size_t)by * 128 * 4096, Bb, As, Bs, acc);
  const int tid = threadIdx.x, ln = tid & 63, wv = tid >> 6;
  const int wr = wv >> 1, wc = wv & 1;
  const int l31 = ln & 31, half = ln >> 5;
  // C/D layout (32x32): col = l31, row = (r&3) + 8*(r>>2) + 4*half
#pragma unroll
  for (int tm = 0; tm < 2; ++tm)
#pragma unroll
    for (int tn = 0; tn < 2; ++tn) {
      int colb = wc * 64 + tn * 32 + l31;  // col within the 128-block
#pragma unroll
      for (int g = 0; g < 4; ++g) {
        int mb = by * 128 + wr * 64 + tm * 32 + g * 8 + half * 4;  // token of reg 4g
        if (bx < 32) {
#pragma unroll
          for (int r2 = 0; r2 < 4; ++r2)
            qh[(size_t)(mb + r2) * 4096 + bx * 128 + colb] = (f16)acc[tm][tn][g * 4 + r2];
        } else if (bx < 40) {
#pragma unroll
          for (int r2 = 0; r2 < 4; ++r2)
            kh[(size_t)(mb + r2) * 1024 + (bx - 32) * 128 + colb] = (f16)acc[tm][tn][g * 4 + r2];
        } else {
          f16x4 v4;
#pragma unroll
          for (int r2 = 0; r2 < 4; ++r2) v4[r2] = (f16)acc[tm][tn][g * 4 + r2];
          int n2 = (bx - 40) * 128 + colb;
          int kv = n2 >> 7, d = n2 & 127;
          int bbv = mb >> 11, sl = mb & 2047;  // 4 consecutive tokens, same batch (mb%4==0)
          *(f16x4*)&vt[(((size_t)bbv * 8 + kv) * 128 + d) * 2048 + sl] = v4;
        }
      }
    }
}

// ---------------- RoPE in-place on Q and K (16B per thread) ----------------
__global__ void rope_qk(f16* __restrict__ qh, f16* __restrict__ kh,
                        const float* __restrict__ fc, const float* __restrict__ fs) {
  int i = blockIdx.x * blockDim.x + threadIdx.x;  // granule = 8 f16 = 4 rot pairs
  const int QG = 4096 * 32 * 16;
  f16* ptr;
  int sl, p0;
  if (i < QG) {
    int g = i & 15, head = (i >> 4) & 31, tok = i >> 9;
    sl = tok & 2047; p0 = g * 4;
    ptr = qh + (size_t)tok * 4096 + head * 128 + g * 8;
  } else {
    int j = i - QG;
    int g = j & 15, head = (j >> 4) & 7, tok = j >> 7;
    sl = tok & 2047; p0 = g * 4;
    ptr = kh + (size_t)tok * 1024 + head * 128 + g * 8;
  }
  f16x8 v = *(f16x8*)ptr;
  float4 c = *(const float4*)&fc[sl * 64 + p0];
  float4 s = *(const float4*)&fs[sl * 64 + p0];
  f16x8 o;
  o[0] = (f16)((float)v[0] * c.x - (float)v[1] * s.x);
  o[1] = (f16)((float)v[0] * s.x + (float)v[1] * c.x);
  o[2] = (f16)((float)v[2] * c.y - (float)v[3] * s.y);
  o[3] = (f16)((float)v[2] * s.y + (float)v[3] * c.y);
  o[4] = (f16)((float)v[4] * c.z - (float)v[5] * s.z);
  o[5] = (f16)((float)v[4] * s.z + (float)v[5] * c.z);
  o[6] = (f16)((float)v[6] * c.w - (float)v[7] * s.w);
  o[7] = (f16)((float)v[6] * s.w + (float)v[7] * c.w);
  *(f16x8*)ptr = o;
}

// ---------------- causal GQA flash attention (transposed S/O formulation) ----------------
// grid (32 qtiles, 32 heads, 2 batch), 4 waves, each wave a 16-query strip (q = lane&15).
// S^T = K Q^T  (lane owns query col q=c16 -> in-lane softmax), O^T = V^T P^T.
__global__ __launch_bounds__(256, 4) void attn(
    const f16* __restrict__ qh, const f16* __restrict__ kh,
    const f16* __restrict__ vt, f16* __restrict__ ao) {
  __shared__ __align__(16) f16 Kl[64 * 128];   // [s][d], granule-swizzled g^(s&15)
  __shared__ __align__(16) f16 Vl[128 * 64];   // [d][s], granule-swizzled g^(d&7)
  __shared__ __align__(16) f16 Pl[4][16 * 64]; // per-wave P [q][k], granule-swizzled g^(q&7)
  const int qt = 31 - blockIdx.x;  // longest blocks dispatch first
  const int h = blockIdx.y, bb = blockIdx.z;
  const int kvh = h >> 2;
  const int tid = threadIdx.x, ln = tid & 63, wv = tid >> 6;
  const int quad = ln >> 4, c16 = ln & 15;

  // Q fragment (A/B layout identical): lane holds Q[q=strip row c16][d = ks*32+quad*8+j]
  f16x8 Qf[4];
  {
    size_t qbase = ((size_t)(bb * 2048 + qt * 64 + wv * 16 + c16)) * 4096 + h * 128;
#pragma unroll
    for (int ks = 0; ks < 4; ++ks)
      Qf[ks] = *(const f16x8*)&qh[qbase + ks * 32 + quad * 8];
  }
  float m_run = -INFINITY, l_run = 0.f;
  f32x4 Ot[8];  // O^T tiles over d; lane col = q
#pragma unroll
  for (int n = 0; n < 8; ++n) { f32x4 z = {0.f, 0.f, 0.f, 0.f}; Ot[n] = z; }
  const float scale = 0.08838834764831843f;  // 1/sqrt(128)
  const int qg = qt * 64 + wv * 16 + c16;    // this lane's global query index
  const int swp = ((quad ^ (c16 & 7)) * 8);         // Pl read swizzle, ks=0
  const int swp1 = (((4 + quad) ^ (c16 & 7)) * 8);  // ks=1

  for (int t = 0; t <= qt; ++t) {
    // stage K tile [64][128] and V^T tile [128][64] (swizzled), 4+4 chunks per wave
#pragma unroll
    for (int c = 0; c < 4; ++c) {
      int chunk = wv * 4 + c;
      int krow = chunk * 4 + (ln >> 4);
      int kg = (ln & 15) ^ (krow & 15);
      gld_lds16(&kh[((size_t)(bb * 2048 + t * 64 + krow)) * 1024 + kvh * 128 + kg * 8],
                &Kl[chunk * 512]);
    }
#pragma unroll
    for (int c = 0; c < 4; ++c) {
      int chunk = wv * 4 + c;
      int vrow = chunk * 8 + (ln >> 3);
      int vg = (ln & 7) ^ (vrow & 7);
      gld_lds16(&vt[(((size_t)bb * 8 + kvh) * 128 + vrow) * 2048 + t * 64 + vg * 8],
                &Vl[chunk * 512]);
    }
    __syncthreads();

    // S^T(64x16 per wave): Sa[tn] = K-tile(tn) x Q^T; D[k'=quad*4+r][q=c16]
    f32x4 Sa[4];
#pragma unroll
    for (int tn = 0; tn < 4; ++tn) {
      f32x4 z = {0.f, 0.f, 0.f, 0.f};
      Sa[tn] = z;
#pragma unroll
      for (int ks = 0; ks < 4; ++ks) {
        f16x8 kf = *(const f16x8*)&Kl[(tn * 16 + c16) * 128 + (((ks * 4 + quad) ^ c16) * 8)];
        Sa[tn] = __builtin_amdgcn_mfma_f32_16x16x32_f16(kf, Qf[ks], Sa[tn], 0, 0, 0);
      }
    }

    // scale + causal mask (diagonal tile only)
#pragma unroll
    for (int tn = 0; tn < 4; ++tn)
#pragma unroll
      for (int r = 0; r < 4; ++r) Sa[tn][r] *= scale;
    if (t == qt) {
#pragma unroll
      for (int tn = 0; tn < 4; ++tn) {
        int kbase = t * 64 + tn * 16 + quad * 4;
#pragma unroll
        for (int r = 0; r < 4; ++r)
          if (kbase + r > qg) Sa[tn][r] = -INFINITY;
      }
    }

    // online softmax: per-lane (one q per lane), 2 shuffles per reduction
    float mm = -INFINITY;
#pragma unroll
    for (int tn = 0; tn < 4; ++tn)
#pragma unroll
      for (int r = 0; r < 4; ++r) mm = fmaxf(mm, Sa[tn][r]);
    mm = fmaxf(mm, __shfl_xor(mm, 16, 64));
    mm = fmaxf(mm, __shfl_xor(mm, 32, 64));
    float mn = fmaxf(m_run, mm);
    float alpha = __expf(m_run - mn);
    m_run = mn;
    float rsum = 0.f;
#pragma unroll
    for (int tn = 0; tn < 4; ++tn)
#pragma unroll
      for (int r = 0; r < 4; ++r) {
        float p = __expf(Sa[tn][r] - mn);
        Sa[tn][r] = p;
        rsum += p;
      }
    rsum += __shfl_xor(rsum, 16, 64);
    rsum += __shfl_xor(rsum, 32, 64);
    l_run = l_run * alpha + rsum;

    // P^T (C-layout) -> Pl[q][k] (8B packed, swizzled)
#pragma unroll
    for (int tn = 0; tn < 4; ++tn) {
      f16x4 pk;
#pragma unroll
      for (int r = 0; r < 4; ++r) pk[r] = (f16)Sa[tn][r];
      int g = tn * 2 + (quad >> 1);
      *(f16x4*)&Pl[wv][c16 * 64 + ((g ^ (c16 & 7)) * 8) + (quad & 1) * 4] = pk;
    }

    // rescale O (alpha is a per-lane scalar)
#pragma unroll
    for (int n = 0; n < 8; ++n)
#pragma unroll
      for (int r = 0; r < 4; ++r) Ot[n][r] *= alpha;

    __asm__ volatile("s_waitcnt lgkmcnt(0)" ::: "memory");  // P writes -> P reads (same wave)

    // O^T += V^T P^T : A=V^T[d][k] frags, B=P^T (= rows of Pl[q][k])
    {
      f16x8 pf0 = *(const f16x8*)&Pl[wv][c16 * 64 + swp];
      f16x8 pf1 = *(const f16x8*)&Pl[wv][c16 * 64 + swp1];
#pragma unroll
      for (int n = 0; n < 8; ++n) {
        int rowv = (n * 16 + c16) * 64;
        f16x8 vf0 = *(const f16x8*)&Vl[rowv + swp];
        Ot[n] = __builtin_amdgcn_mfma_f32_16x16x32_f16(vf0, pf0, Ot[n], 0, 0, 0);
        f16x8 vf1 = *(const f16x8*)&Vl[rowv + swp1];
        Ot[n] = __builtin_amdgcn_mfma_f32_16x16x32_f16(vf1, pf1, Ot[n], 0, 0, 0);
      }
    }
    __syncthreads();
  }

  // epilogue: O = O^T normalized; lane writes 4 contiguous d per tile (8B stores)
  float inv = 1.0f / l_run;
  size_t token = (size_t)(bb * 2048 + qt * 64 + wv * 16 + c16);
#pragma unroll
  for (int n = 0; n < 8; ++n) {
    f16x4 o;
#pragma unroll
    for (int r = 0; r < 4; ++r) o[r] = (f16)(Ot[n][r] * inv);
    *(f16x4*)&ao[token * 4096 + h * 128 + n * 16 + quad * 4] = o;
  }
}

// ---------------- output projection: out = ao @ wo^T (fp32 out) ----------------
__global__ __launch_bounds__(256, 4) void gemm_out(
    const f16* __restrict__ ao, const f16* __restrict__ woh, float* __restrict__ out) {
  __shared__ __align__(16) f16 As[4096];
  __shared__ __align__(16) f16 Bs[4096];
  f32x16 acc[2][2];
  gemm_core_4096(ao + (size_t)blockIdx.y * 128 * 4096,
                 woh + (size_t)blockIdx.x * 128 * 4096, As, Bs, acc);
  const int tid = threadIdx.x, ln = tid & 63, wv = tid >> 6;
  const int wr = wv >> 1, wc = wv & 1;
  const int l31 = ln & 31, half = ln >> 5;
#pragma unroll
  for (int tm = 0; tm < 2; ++tm)
#pragma unroll
    for (int tn = 0; tn < 2; ++tn) {
      int n = blockIdx.x * 128 + wc * 64 + tn * 32 + l31;
#pragma unroll
      for (int g = 0; g < 4; ++g) {
        int mb = blockIdx.y * 128 + wr * 64 + tm * 32 + g * 8 + half * 4;
#pragma unroll
        for (int r2 = 0; r2 < 4; ++r2)
          out[(size_t)(mb + r2) * 4096 + n] = acc[tm][tn][g * 4 + r2];
      }
    }
}

// ---------------- launch ----------------
extern "C" void kernel_launch(void* const* d_in, const int* in_sizes, int n_in,
                              void* d_out, int out_size, void* d_ws, size_t ws_size,
                              hipStream_t stream) {
  const float* x  = (const float*)d_in[0];
  const float* wq = (const float*)d_in[1];
  const float* wk = (const float*)d_in[2];
  const float* wv = (const float*)d_in[3];
  const float* wo = (const float*)d_in[4];
  const float* fc = (const float*)d_in[5];
  const float* fs = (const float*)d_in[6];
  float* out = (float*)d_out;

  char* ws = (char*)d_ws;
  f16* xh  = (f16*)(ws + 0);          // 32 MiB  x fp16 [4096][4096]
  f16* wqh = (f16*)(ws + 33554432);   // 32 MiB
  f16* wkh = (f16*)(ws + 67108864);   // 8 MiB
  f16* wvh = (f16*)(ws + 75497472);   // 8 MiB
  f16* woh = (f16*)(ws + 83886080);   // 32 MiB
  f16* qh  = (f16*)(ws + 117440512);  // 32 MiB  Q [4096][4096]
  f16* kh  = (f16*)(ws + 150994944);  // 8 MiB   K [4096][1024]
  f16* vt  = (f16*)(ws + 159383552);  // 8 MiB   V^T [2][8][128][2048]
  f16* ao  = (f16*)(ws + 167772160);  // 32 MiB  attn out [4096][4096]

  cast_all<<<57344, 256, 0, stream>>>(x, wq, wk, wv, wo, xh, wqh, wkh, wvh, woh);
  gemm_qkv<<<dim3(48, 32), 256, 0, stream>>>(xh, wqh, wkh, wvh, qh, kh, vt);
  rope_qk<<<10240, 256, 0, stream>>>(qh, kh, fc, fs);
  attn<<<dim3(32, 32, 2), 256, 0, stream>>>(qh, kh, vt, ao);
  gemm_out<<<dim3(32, 32), 256, 0, stream>>>(ao, woh, out);
}